// Round 2
// baseline (9752.344 us; speedup 1.0000x reference)
//
#include <hip/hip_runtime.h>
#include <hip/hip_cooperative_groups.h>

// Problem constants (G=1024 grid, known structure)
#define GSZ   1024
#define NV    (GSZ*GSZ)           // 1048576 vertices
#define N3    (NV*3)              // floats per [NV,3] array
#define FH    ((GSZ-1)*(GSZ-1))   // faces in first half
#define NF    (2*FH)              // total faces
#define O1    N3                  // centroid offset in d_out (floats)
#define O2    (O1 + 3*NF)         // fn offset
#define O3    (O2 + 3*NF)         // vn offset
#define LAMBDA 10.0f
#define CG_ITERS 64

#define NBLK 256
#define NTHR 512
#define KPT  8                    // vertices per thread: 256*512*8 = NV
#define NWAVE (NTHR/64)

namespace cg = cooperative_groups;

// Persistent Chronopoulos-Gear CG.
// State per thread (registers): x, p, s, w, own r  (KPT vertices x 3 comps).
// Global: r in 3 SoA planes (stencil neighbors), partials[2*NBLK] doubles.
// Recurrence (identical to standard CG in exact arithmetic):
//   w = A r; gamma=(r,r); delta=(w,r)
//   beta = gamma/gamma_old; alpha = gamma/(delta - beta*gamma/alpha_old)
//   p = r + beta p; s = w + beta s; x += alpha p; r -= alpha s
__global__ void __launch_bounds__(NTHR, 2)
k_cg_persist(const float* __restrict__ u, float* __restrict__ verts,
             float* __restrict__ rg, double* __restrict__ partials) {
  cg::grid_group grid = cg::this_grid();
  const int tid = threadIdx.x;
  const int blk = blockIdx.x;
  const int vbase = blk * (NTHR * KPT);
  float* rx = rg;
  float* ry = rg + NV;
  float* rz = rg + 2 * NV;

  __shared__ double sm[2 * NWAVE];
  __shared__ double sbc[2];

  float x0[KPT], x1[KPT], x2[KPT];
  float p0[KPT], p1[KPT], p2[KPT];
  float s0[KPT], s1[KPT], s2[KPT];
  float r0[KPT], r1[KPT], r2[KPT];
  float w0[KPT], w1[KPT], w2[KPT];

  // ---- init: r = u, x = 0, p = s = 0; publish r planes ----
#pragma unroll
  for (int k = 0; k < KPT; ++k) {
    int v = vbase + k * NTHR + tid;
    r0[k] = u[3*v]; r1[k] = u[3*v+1]; r2[k] = u[3*v+2];
    x0[k] = x1[k] = x2[k] = 0.f;
    p0[k] = p1[k] = p2[k] = 0.f;
    s0[k] = s1[k] = s2[k] = 0.f;
    rx[v] = r0[k]; ry[v] = r1[k]; rz[v] = r2[k];
  }
  __threadfence();
  grid.sync();

  double gamma_old = 1.0, alpha_old = 1.0;

  for (int it = 0; it < CG_ITERS; ++it) {
    // ---- phase A: w = A r (6-neighbor stencil), rr=(r,r), rw=(w,r) ----
    double rr = 0.0, rw = 0.0;
#pragma unroll
    for (int k = 0; k < KPT; ++k) {
      int v = vbase + k * NTHR + tid;
      int i = v >> 10, j = v & (GSZ - 1);
      float n0 = 0.f, n1 = 0.f, n2 = 0.f;
      int deg = 0;
      if (j > 0)                { n0 += rx[v-1];    n1 += ry[v-1];    n2 += rz[v-1];    deg++; }
      if (j < GSZ-1)            { n0 += rx[v+1];    n1 += ry[v+1];    n2 += rz[v+1];    deg++; }
      if (i > 0)                { n0 += rx[v-GSZ];  n1 += ry[v-GSZ];  n2 += rz[v-GSZ];  deg++; }
      if (i < GSZ-1)            { n0 += rx[v+GSZ];  n1 += ry[v+GSZ];  n2 += rz[v+GSZ];  deg++; }
      if (i < GSZ-1 && j > 0)   { n0 += rx[v+GSZ-1]; n1 += ry[v+GSZ-1]; n2 += rz[v+GSZ-1]; deg++; }
      if (i > 0 && j < GSZ-1)   { n0 += rx[v-GSZ+1]; n1 += ry[v-GSZ+1]; n2 += rz[v-GSZ+1]; deg++; }
      float diag = 1.0f + LAMBDA * (float)deg;
      float a0 = diag * r0[k] - LAMBDA * n0;
      float a1 = diag * r1[k] - LAMBDA * n1;
      float a2 = diag * r2[k] - LAMBDA * n2;
      w0[k] = a0; w1[k] = a1; w2[k] = a2;
      rr += (double)r0[k]*r0[k] + (double)r1[k]*r1[k] + (double)r2[k]*r2[k];
      rw += (double)a0*r0[k] + (double)a1*r1[k] + (double)a2*r2[k];
    }
    // block-reduce (deterministic): wave butterfly -> shared -> thread 0
#pragma unroll
    for (int off = 32; off > 0; off >>= 1) {
      rr += __shfl_down(rr, off, 64);
      rw += __shfl_down(rw, off, 64);
    }
    if ((tid & 63) == 0) { sm[2*(tid>>6)] = rr; sm[2*(tid>>6)+1] = rw; }
    __syncthreads();
    if (tid == 0) {
      double ta = 0.0, tb = 0.0;
      for (int wv = 0; wv < NWAVE; ++wv) { ta += sm[2*wv]; tb += sm[2*wv+1]; }
      partials[2*blk] = ta; partials[2*blk+1] = tb;
      __threadfence();
    }
    grid.sync();

    // ---- phase B: every block reduces partials -> scalars, then update ----
    double pa = 0.0, pb = 0.0;
    if (tid < NBLK) { pa = partials[2*tid]; pb = partials[2*tid+1]; }
#pragma unroll
    for (int off = 32; off > 0; off >>= 1) {
      pa += __shfl_down(pa, off, 64);
      pb += __shfl_down(pb, off, 64);
    }
    if ((tid & 63) == 0) { sm[2*(tid>>6)] = pa; sm[2*(tid>>6)+1] = pb; }
    __syncthreads();
    if (tid == 0) {
      double ta = 0.0, tb = 0.0;
      for (int wv = 0; wv < NWAVE; ++wv) { ta += sm[2*wv]; tb += sm[2*wv+1]; }
      sbc[0] = ta; sbc[1] = tb;
    }
    __syncthreads();
    double gamma = sbc[0], delta = sbc[1];
    double beta, alpha;
    if (it == 0) { beta = 0.0; alpha = gamma / delta; }
    else {
      beta  = gamma / gamma_old;
      alpha = gamma / (delta - beta * gamma / alpha_old);
    }
    gamma_old = gamma; alpha_old = alpha;
    float bf = (float)beta, af = (float)alpha;
#pragma unroll
    for (int k = 0; k < KPT; ++k) {
      int v = vbase + k * NTHR + tid;
      p0[k] = r0[k] + bf * p0[k];
      p1[k] = r1[k] + bf * p1[k];
      p2[k] = r2[k] + bf * p2[k];
      s0[k] = w0[k] + bf * s0[k];
      s1[k] = w1[k] + bf * s1[k];
      s2[k] = w2[k] + bf * s2[k];
      x0[k] += af * p0[k];
      x1[k] += af * p1[k];
      x2[k] += af * p2[k];
      r0[k] -= af * s0[k];
      r1[k] -= af * s1[k];
      r2[k] -= af * s2[k];
      rx[v] = r0[k]; ry[v] = r1[k]; rz[v] = r2[k];
    }
    __threadfence();
    grid.sync();
  }

  // ---- write verts (interleaved [NV,3]) ----
#pragma unroll
  for (int k = 0; k < KPT; ++k) {
    int v = vbase + k * NTHR + tid;
    verts[3*v] = x0[k]; verts[3*v+1] = x1[k]; verts[3*v+2] = x2[k];
  }
}

// per-face centroid + normalized cross
__global__ __launch_bounds__(256) void k_faces(const float* __restrict__ v,
    float* __restrict__ cen, float* __restrict__ fn) {
  int f = blockIdx.x * 256 + threadIdx.x;
  if (f >= NF) return;
  int second = (f >= FH) ? 1 : 0;
  int cell = second ? f - FH : f;
  int ci = cell / (GSZ-1);
  int cj = cell - ci * (GSZ-1);
  int v00 = ci * GSZ + cj;
  int a0, a1, a2;
  if (!second) { a0 = v00;     a1 = v00 + 1;       a2 = v00 + GSZ; }
  else         { a0 = v00 + 1; a1 = v00 + GSZ + 1; a2 = v00 + GSZ; }
  float x0 = v[3*a0], y0 = v[3*a0+1], z0 = v[3*a0+2];
  float x1 = v[3*a1], y1 = v[3*a1+1], z1 = v[3*a1+2];
  float x2 = v[3*a2], y2 = v[3*a2+1], z2 = v[3*a2+2];
  const float third = 1.0f / 3.0f;
  cen[3*f]   = (x0 + x1 + x2) * third;
  cen[3*f+1] = (y0 + y1 + y2) * third;
  cen[3*f+2] = (z0 + z1 + z2) * third;
  float ax = x1-x0, ay = y1-y0, az = z1-z0;
  float bx = x2-x0, by = y2-y0, bz = z2-z0;
  float cx = ay*bz - az*by;
  float cy = az*bx - ax*bz;
  float cz = ax*by - ay*bx;
  float nrm = sqrtf(cx*cx + cy*cy + cz*cz);
  float inv = 1.0f / fmaxf(nrm, 1e-12f);
  fn[3*f] = cx*inv; fn[3*f+1] = cy*inv; fn[3*f+2] = cz*inv;
}

// per-vertex: gather <=6 adjacent face normals, sum, normalize
__global__ __launch_bounds__(256) void k_vn(const float* __restrict__ fn,
    float* __restrict__ vn) {
  int t = blockIdx.x * 256 + threadIdx.x;
  int i = t >> 10, j = t & (GSZ - 1);
  float s0 = 0.f, s1 = 0.f, s2 = 0.f;
  bool iN = (i >= 1), iS = (i <= GSZ-2), jW = (j >= 1), jE = (j <= GSZ-2);
  int rowi = i * (GSZ-1);
#define ADD(fidx) { int f_ = (fidx); s0 += fn[3*f_]; s1 += fn[3*f_+1]; s2 += fn[3*f_+2]; }
  if (iS && jE) ADD(rowi + j);
  if (iS && jW) ADD(rowi + j - 1);
  if (iN && jE) ADD(rowi - (GSZ-1) + j);
  if (iS && jW) ADD(FH + rowi + j - 1);
  if (iN && jW) ADD(FH + rowi - (GSZ-1) + j - 1);
  if (iN && jE) ADD(FH + rowi - (GSZ-1) + j);
#undef ADD
  float nrm = sqrtf(s0*s0 + s1*s1 + s2*s2);
  float inv = 1.0f / fmaxf(nrm, 1e-12f);
  vn[3*t] = s0*inv; vn[3*t+1] = s1*inv; vn[3*t+2] = s2*inv;
}

extern "C" void kernel_launch(void* const* d_in, const int* in_sizes, int n_in,
                              void* d_out, int out_size, void* d_ws, size_t ws_size,
                              hipStream_t stream) {
  const float* u = (const float*)d_in[0];
  float* out = (float*)d_out;

  float* x   = out;        // verts
  float* cen = out + O1;
  float* fn  = out + O2;
  float* vn  = out + O3;

  // CG scratch in the tail of d_out (cen region, overwritten after CG):
  // r planes: 3*NV floats (12.6 MB), then partials (512 doubles, 8B-aligned).
  float*  rg       = out + O1;
  double* partials = (double*)(out + O1 + 3 * NV);

  void* kargs[4] = { (void*)&u, (void*)&x, (void*)&rg, (void*)&partials };
  hipLaunchCooperativeKernel((const void*)k_cg_persist, dim3(NBLK), dim3(NTHR),
                             kargs, 0, stream);

  k_faces<<<dim3((NF + 255)/256), dim3(256), 0, stream>>>(x, cen, fn);
  k_vn<<<dim3(NV/256), dim3(256), 0, stream>>>(fn, vn);
}

// Round 3
// 4261.537 us; speedup vs baseline: 2.2885x; 2.2885x over previous
//
#include <hip/hip_runtime.h>

// Problem constants (G=1024 grid, known structure)
#define GSZ   1024
#define NV    (GSZ*GSZ)           // 1048576 vertices
#define N3    (NV*3)              // floats per [NV,3] array
#define FH    ((GSZ-1)*(GSZ-1))   // faces in first half
#define NF    (2*FH)              // total faces
#define O1    N3                  // centroid offset in d_out (floats)
#define O2    (O1 + 3*NF)         // fn offset
#define O3    (O2 + 3*NF)         // vn offset
#define LAM   10.0f
#define CG_ITERS 64

#define NBLK 256                  // grid blocks for CG kernels (1 per CU)
#define NTHR 1024                 // threads per block (j = tid)
#define RPB  4                    // rows per block: 256*4 = 1024 rows

// ---------- deterministic reductions ----------
// sum over this block's 1024 threads; result valid on thread 0 only
__device__ __forceinline__ double blk_reduce_to0(double v, double* sm) {
#pragma unroll
  for (int off = 32; off > 0; off >>= 1) v += __shfl_down(v, off, 64);
  int w = threadIdx.x >> 6;
  if ((threadIdx.x & 63) == 0) sm[w] = v;
  __syncthreads();
  double s = 0.0;
  if (threadIdx.x == 0) {
#pragma unroll
    for (int k = 0; k < 16; ++k) s += sm[k];
  }
  return s;
}

// sum part[0..NBLK), broadcast identical value to all threads (fixed order)
__device__ __forceinline__ double all_reduce_part(const double* __restrict__ part,
                                                  double* sm) {
  int tid = threadIdx.x;
  double v = (tid < NBLK) ? part[tid] : 0.0;
#pragma unroll
  for (int off = 32; off > 0; off >>= 1) v += __shfl_down(v, off, 64);
  if ((tid & 63) == 0 && (tid >> 6) < 4) sm[tid >> 6] = v;
  __syncthreads();
  double s = sm[0] + sm[1] + sm[2] + sm[3];
  __syncthreads();
  return s;
}

// 6-neighbor sum of one SoA plane at v=(i,j)
__device__ __forceinline__ float nsum1(const float* __restrict__ a, int v,
                                       bool jm, bool jp, bool im, bool ip) {
  float s = 0.f;
  if (jm)       s += a[v - 1];
  if (jp)       s += a[v + 1];
  if (im)       s += a[v - GSZ];
  if (ip)       s += a[v + GSZ];
  if (ip && jm) s += a[v + GSZ - 1];   // (i+1, j-1)
  if (im && jp) s += a[v - GSZ + 1];   // (i-1, j+1)
  return s;
}

// ---------- init: r = u (planes), partRR0 = per-block (u,u) ----------
__global__ __launch_bounds__(NTHR) void k_init(const float* __restrict__ u,
    float* __restrict__ r, double* __restrict__ partRR0) {
  __shared__ double sm[16];
  int j = threadIdx.x;
  double rr = 0.0;
#pragma unroll
  for (int k = 0; k < RPB; ++k) {
    int i = blockIdx.x * RPB + k;
    int v = (i << 10) + j;
    float a = u[3*v], b = u[3*v+1], c = u[3*v+2];
    r[v] = a; r[NV + v] = b; r[2*NV + v] = c;
    rr += (double)a*a + (double)b*b + (double)c*c;
  }
  double tot = blk_reduce_to0(rr, sm);
  if (threadIdx.x == 0) partRR0[blockIdx.x] = tot;
}

// ---------- k1: beta, p_new = r + beta*p_old, partPQ = (p_new, A p_new) ----------
__global__ __launch_bounds__(NTHR) void k1(const float* __restrict__ r,
    const float* __restrict__ pOld, float* __restrict__ pNew,
    const double* __restrict__ partRR, const double* __restrict__ slotPrev,
    double* __restrict__ slotNext, double* __restrict__ partPQ, int it) {
  __shared__ double sm[16];
  double gcur = all_reduce_part(partRR, sm);
  double beta = (it > 0) ? (gcur / slotPrev[0]) : 0.0;
  if (blockIdx.x == 0 && threadIdx.x == 0) slotNext[0] = gcur;
  float bf = (float)beta;

  int j = threadIdx.x;
  bool jm = (j > 0), jp = (j < GSZ - 1);
  double pq = 0.0;
#pragma unroll
  for (int k = 0; k < RPB; ++k) {
    int i = blockIdx.x * RPB + k;
    int v = (i << 10) + j;
    bool im = (i > 0), ip = (i < GSZ - 1);
    int deg = (int)jm + (int)jp + (int)im + (int)ip
            + (int)(ip && jm) + (int)(im && jp);
    float diag = 1.0f + LAM * (float)deg;
#pragma unroll
    for (int c = 0; c < 3; ++c) {
      const float* rp = r    + c * NV;
      const float* pp = pOld + c * NV;
      float pv = rp[v] + bf * pp[v];
      float ns = nsum1(rp, v, jm, jp, im, ip) + bf * nsum1(pp, v, jm, jp, im, ip);
      float q  = diag * pv - LAM * ns;
      pNew[c * NV + v] = pv;
      pq += (double)pv * (double)q;
    }
  }
  double tot = blk_reduce_to0(pq, sm);
  if (threadIdx.x == 0) partPQ[blockIdx.x] = tot;
}

// ---------- k2: alpha, x += alpha p, r -= alpha (A p), partRR' = (r,r) ----------
__global__ __launch_bounds__(NTHR) void k2(const float* __restrict__ pNew,
    float* __restrict__ r, float* __restrict__ x,
    const double* __restrict__ partPQ, const double* __restrict__ partRRcur,
    double* __restrict__ partRRnext, int it) {
  __shared__ double sm[16];
  double pq   = all_reduce_part(partPQ, sm);
  double gcur = all_reduce_part(partRRcur, sm);
  float af = (float)(gcur / pq);

  int j = threadIdx.x;
  bool jm = (j > 0), jp = (j < GSZ - 1);
  double rr = 0.0;
#pragma unroll
  for (int k = 0; k < RPB; ++k) {
    int i = blockIdx.x * RPB + k;
    int v = (i << 10) + j;
    bool im = (i > 0), ip = (i < GSZ - 1);
    int deg = (int)jm + (int)jp + (int)im + (int)ip
            + (int)(ip && jm) + (int)(im && jp);
    float diag = 1.0f + LAM * (float)deg;
#pragma unroll
    for (int c = 0; c < 3; ++c) {
      const float* pp = pNew + c * NV;
      int cv = c * NV + v;
      float pv = pp[v];
      float ns = nsum1(pp, v, jm, jp, im, ip);
      float q  = diag * pv - LAM * ns;
      float rn = r[cv] - af * q;
      r[cv] = rn;
      if (it == 0) x[cv] = af * pv;
      else         x[cv] += af * pv;
      rr += (double)rn * (double)rn;
    }
  }
  double tot = blk_reduce_to0(rr, sm);
  if (threadIdx.x == 0) partRRnext[blockIdx.x] = tot;
}

// ---------- x planes -> interleaved verts ----------
__global__ __launch_bounds__(NTHR) void k_xvert(const float* __restrict__ x,
    float* __restrict__ verts) {
  int j = threadIdx.x;
#pragma unroll
  for (int k = 0; k < RPB; ++k) {
    int i = blockIdx.x * RPB + k;
    int v = (i << 10) + j;
    verts[3*v]   = x[v];
    verts[3*v+1] = x[NV + v];
    verts[3*v+2] = x[2*NV + v];
  }
}

// ---------- per-face centroid + normalized cross ----------
__global__ __launch_bounds__(256) void k_faces(const float* __restrict__ v,
    float* __restrict__ cen, float* __restrict__ fn) {
  int f = blockIdx.x * 256 + threadIdx.x;
  if (f >= NF) return;
  int second = (f >= FH) ? 1 : 0;
  int cell = second ? f - FH : f;
  int ci = cell / (GSZ-1);
  int cj = cell - ci * (GSZ-1);
  int v00 = ci * GSZ + cj;
  int a0, a1, a2;
  if (!second) { a0 = v00;     a1 = v00 + 1;       a2 = v00 + GSZ; }
  else         { a0 = v00 + 1; a1 = v00 + GSZ + 1; a2 = v00 + GSZ; }
  float x0 = v[3*a0], y0 = v[3*a0+1], z0 = v[3*a0+2];
  float x1 = v[3*a1], y1 = v[3*a1+1], z1 = v[3*a1+2];
  float x2 = v[3*a2], y2 = v[3*a2+1], z2 = v[3*a2+2];
  const float third = 1.0f / 3.0f;
  cen[3*f]   = (x0 + x1 + x2) * third;
  cen[3*f+1] = (y0 + y1 + y2) * third;
  cen[3*f+2] = (z0 + z1 + z2) * third;
  float ax = x1-x0, ay = y1-y0, az = z1-z0;
  float bx = x2-x0, by = y2-y0, bz = z2-z0;
  float cx = ay*bz - az*by;
  float cy = az*bx - ax*bz;
  float cz = ax*by - ay*bx;
  float nrm = sqrtf(cx*cx + cy*cy + cz*cz);
  float inv = 1.0f / fmaxf(nrm, 1e-12f);
  fn[3*f] = cx*inv; fn[3*f+1] = cy*inv; fn[3*f+2] = cz*inv;
}

// ---------- per-vertex normal: gather <=6 adjacent faces ----------
__global__ __launch_bounds__(256) void k_vn(const float* __restrict__ fn,
    float* __restrict__ vn) {
  int t = blockIdx.x * 256 + threadIdx.x;
  int i = t >> 10, j = t & (GSZ - 1);
  float s0 = 0.f, s1 = 0.f, s2 = 0.f;
  bool iN = (i >= 1), iS = (i <= GSZ-2), jW = (j >= 1), jE = (j <= GSZ-2);
  int rowi = i * (GSZ-1);
#define ADD(fidx) { int f_ = (fidx); s0 += fn[3*f_]; s1 += fn[3*f_+1]; s2 += fn[3*f_+2]; }
  if (iS && jE) ADD(rowi + j);
  if (iS && jW) ADD(rowi + j - 1);
  if (iN && jE) ADD(rowi - (GSZ-1) + j);
  if (iS && jW) ADD(FH + rowi + j - 1);
  if (iN && jW) ADD(FH + rowi - (GSZ-1) + j - 1);
  if (iN && jE) ADD(FH + rowi - (GSZ-1) + j);
#undef ADD
  float nrm = sqrtf(s0*s0 + s1*s1 + s2*s2);
  float inv = 1.0f / fmaxf(nrm, 1e-12f);
  vn[3*t] = s0*inv; vn[3*t+1] = s1*inv; vn[3*t+2] = s2*inv;
}

extern "C" void kernel_launch(void* const* d_in, const int* in_sizes, int n_in,
                              void* d_out, int out_size, void* d_ws, size_t ws_size,
                              hipStream_t stream) {
  const float* u = (const float*)d_in[0];
  float* out = (float*)d_out;

  float* verts = out;
  float* cen   = out + O1;
  float* fn    = out + O2;
  float* vn    = out + O3;

  // Scratch in d_out tail past verts (cen/fn/vn written only after CG):
  // planes: x(3), r(3), pbuf0(3), pbuf1(3) = 12 planes (48 MB), then doubles.
  float* S     = out + O1;
  float* xpl   = S;
  float* rpl   = S + 3 * (size_t)NV;
  float* pb[2] = { S + 6 * (size_t)NV, S + 9 * (size_t)NV };
  double* D    = (double*)(S + 12 * (size_t)NV);
  double* partRR = D;          // [2][NBLK] parity-buffered
  double* partPQ = D + 2*NBLK; // [NBLK]
  double* slots  = D + 3*NBLK; // [2] gamma parity slots

  k_init<<<dim3(NBLK), dim3(NTHR), 0, stream>>>(u, rpl, partRR /*parity 0*/);

  for (int it = 0; it < CG_ITERS; ++it) {
    const double* prrCur = partRR + (it & 1) * NBLK;
    double*       prrNxt = partRR + ((it + 1) & 1) * NBLK;
    const float*  pOld   = pb[it & 1];
    float*        pNew   = pb[(it + 1) & 1];
    k1<<<dim3(NBLK), dim3(NTHR), 0, stream>>>(rpl, pOld, pNew,
        prrCur, &slots[it & 1], &slots[(it + 1) & 1], partPQ, it);
    k2<<<dim3(NBLK), dim3(NTHR), 0, stream>>>(pNew, rpl, xpl,
        partPQ, prrCur, prrNxt, it);
  }

  k_xvert<<<dim3(NBLK), dim3(NTHR), 0, stream>>>(xpl, verts);
  k_faces<<<dim3((NF + 255)/256), dim3(256), 0, stream>>>(verts, cen, fn);
  k_vn<<<dim3(NV/256), dim3(256), 0, stream>>>(fn, vn);
}

// Round 5
// 1394.219 us; speedup vs baseline: 6.9948x; 3.0566x over previous
//
#include <hip/hip_runtime.h>

// Problem constants (G=1024 grid, known structure)
#define GSZ   1024
#define NV    (GSZ*GSZ)           // 1048576 vertices
#define N3    (NV*3)              // floats per [NV,3] array
#define FH    ((GSZ-1)*(GSZ-1))   // faces in first half
#define NF    (2*FH)              // total faces
#define O1    N3                  // centroid offset in d_out (floats)
#define O2    (O1 + 3*NF)         // fn offset
#define O3    (O2 + 3*NF)         // vn offset
#define LAM   10.0f
#define CG_ITERS 64

#define NBLK 1024                 // one block per row
#define NTHR 256                  // thread t covers cols 4t..4t+3

typedef float f4u __attribute__((ext_vector_type(4), aligned(4)));

// XCD-band swizzle: XCD x owns rows [128x, 128x+128)
__device__ __forceinline__ int swz_row(int b) { return ((b & 7) << 7) + (b >> 3); }

// ---------- deterministic reductions (256-thread blocks) ----------
__device__ __forceinline__ double blk_reduce_to0(double v, double* sm) {
#pragma unroll
  for (int off = 32; off > 0; off >>= 1) v += __shfl_down(v, off, 64);
  int tid = threadIdx.x;
  if ((tid & 63) == 0) sm[tid >> 6] = v;
  __syncthreads();
  double s = 0.0;
  if (tid == 0) s = sm[0] + sm[1] + sm[2] + sm[3];
  __syncthreads();
  return s;
}

// sum part[0..1024), identical broadcast value on all threads, fixed order
__device__ __forceinline__ double all_reduce_1024(const double* __restrict__ part,
                                                  double* sm) {
  int tid = threadIdx.x;
  double v = part[tid] + part[tid + 256] + part[tid + 512] + part[tid + 768];
#pragma unroll
  for (int off = 32; off > 0; off >>= 1) v += __shfl_down(v, off, 64);
  if ((tid & 63) == 0) sm[tid >> 6] = v;
  __syncthreads();
  double s = sm[0] + sm[1] + sm[2] + sm[3];
  __syncthreads();
  return s;
}

// ---------- vectorized stencil halo (exec-uniform: all 256 threads) ----------
struct Halo { float m[4], u[4], d[4]; float mL, mR, uR, dL; };

__device__ __forceinline__ Halo load_halo(const float* __restrict__ pl,
                                          int i, int t, int base) {
  Halo h;
  float4 v = *(const float4*)(pl + base);
  h.m[0] = v.x; h.m[1] = v.y; h.m[2] = v.z; h.m[3] = v.w;
  if (i > 0) {
    v = *(const float4*)(pl + base - GSZ);
    h.u[0] = v.x; h.u[1] = v.y; h.u[2] = v.z; h.u[3] = v.w;
  } else { h.u[0] = h.u[1] = h.u[2] = h.u[3] = 0.f; }
  if (i < GSZ - 1) {
    v = *(const float4*)(pl + base + GSZ);
    h.d[0] = v.x; h.d[1] = v.y; h.d[2] = v.z; h.d[3] = v.w;
  } else { h.d[0] = h.d[1] = h.d[2] = h.d[3] = 0.f; }
  h.mR = __shfl_down(h.m[0], 1, 64);
  h.uR = __shfl_down(h.u[0], 1, 64);
  h.mL = __shfl_up(h.m[3], 1, 64);
  h.dL = __shfl_up(h.d[3], 1, 64);
  int lane = t & 63;
  if (lane == 63) {
    if (t == 255) { h.mR = 0.f; h.uR = 0.f; }
    else { h.mR = pl[base + 4]; h.uR = (i > 0) ? pl[base - GSZ + 4] : 0.f; }
  }
  if (lane == 0) {
    if (t == 0) { h.mL = 0.f; h.dL = 0.f; }
    else { h.mL = pl[base - 1]; h.dL = (i < GSZ - 1) ? pl[base + GSZ - 1] : 0.f; }
  }
  return h;
}

__device__ __forceinline__ void nsum4(const Halo& h, float ns[4]) {
  ns[0] = h.mL   + h.m[1] + h.u[0] + h.d[0] + h.dL   + h.u[1];
  ns[1] = h.m[0] + h.m[2] + h.u[1] + h.d[1] + h.d[0] + h.u[2];
  ns[2] = h.m[1] + h.m[3] + h.u[2] + h.d[2] + h.d[1] + h.u[3];
  ns[3] = h.m[2] + h.mR   + h.u[3] + h.d[3] + h.d[2] + h.uR;
}

__device__ __forceinline__ void diag4(int i, int t, float dg[4]) {
  bool im = (i > 0), ip = (i < GSZ - 1);
#pragma unroll
  for (int k = 0; k < 4; ++k) {
    bool jm = (k > 0) || (t > 0);
    bool jp = (k < 3) || (t < 255);
    int deg = (int)jm + (int)jp + (int)im + (int)ip
            + (int)(ip && jm) + (int)(im && jp);
    dg[k] = 1.0f + LAM * (float)deg;
  }
}

// ---------- init: u (interleaved) -> r planes, partRR0 = (u,u) ----------
__global__ __launch_bounds__(NTHR, 4) void k_init(const float* __restrict__ u,
    float* __restrict__ r, double* __restrict__ partRR0) {
  __shared__ double sm[4];
  int t = threadIdx.x;
  int i = swz_row(blockIdx.x);
  int vtx = (i << 10) + (t << 2);
  float4 a = *(const float4*)(u + 3 * vtx);
  float4 b = *(const float4*)(u + 3 * vtx + 4);
  float4 c = *(const float4*)(u + 3 * vtx + 8);
  float4 xs = make_float4(a.x, a.w, b.z, c.y);
  float4 ys = make_float4(a.y, b.x, b.w, c.z);
  float4 zs = make_float4(a.z, b.y, c.x, c.w);
  *(float4*)(r + vtx)          = xs;
  *(float4*)(r + NV + vtx)     = ys;
  *(float4*)(r + 2 * NV + vtx) = zs;
  double rr = (double)xs.x*xs.x + (double)xs.y*xs.y + (double)xs.z*xs.z + (double)xs.w*xs.w
            + (double)ys.x*ys.x + (double)ys.y*ys.y + (double)ys.z*ys.z + (double)ys.w*ys.w
            + (double)zs.x*zs.x + (double)zs.y*zs.y + (double)zs.z*zs.z + (double)zs.w*zs.w;
  double tot = blk_reduce_to0(rr, sm);
  if (t == 0) partRR0[blockIdx.x] = tot;
}

// ---------- k1: beta, p_new = r + beta*p_old, partPQ = (p_new, A p_new) ----------
__global__ __launch_bounds__(NTHR, 4) void k1(const float* __restrict__ r,
    const float* __restrict__ pOld, float* __restrict__ pNew,
    const double* __restrict__ partRR, const double* __restrict__ slotPrev,
    double* __restrict__ slotNext, double* __restrict__ partPQ, int it) {
  __shared__ double sm[4];
  double gcur = all_reduce_1024(partRR, sm);
  double beta = (it > 0) ? (gcur / slotPrev[0]) : 0.0;
  if (blockIdx.x == 0 && threadIdx.x == 0) slotNext[0] = gcur;
  float bf = (float)beta;

  int t = threadIdx.x;
  int i = swz_row(blockIdx.x);
  int base = (i << 10) + (t << 2);
  float dg[4]; diag4(i, t, dg);

  double pq = 0.0;
#pragma unroll
  for (int c = 0; c < 3; ++c) {
    Halo hr = load_halo(r    + c * NV, i, t, base);
    Halo hp = load_halo(pOld + c * NV, i, t, base);
    float nr[4], np[4]; nsum4(hr, nr); nsum4(hp, np);
    float pw[4];
#pragma unroll
    for (int k = 0; k < 4; ++k) {
      float pv = hr.m[k] + bf * hp.m[k];
      float ns = nr[k] + bf * np[k];
      float q  = dg[k] * pv - LAM * ns;
      pw[k] = pv;
      pq += (double)pv * (double)q;
    }
    *(float4*)(pNew + c * NV + base) = make_float4(pw[0], pw[1], pw[2], pw[3]);
  }
  double tot = blk_reduce_to0(pq, sm);
  if (t == 0) partPQ[blockIdx.x] = tot;
}

// ---------- k2: alpha, x += alpha p, r -= alpha (A p), partRR' = (r,r) ----------
__global__ __launch_bounds__(NTHR, 4) void k2(const float* __restrict__ pNew,
    float* __restrict__ r, float* __restrict__ x,
    const double* __restrict__ partPQ, const double* __restrict__ partRRcur,
    double* __restrict__ partRRnext, int it) {
  __shared__ double sm[4];
  double pqt  = all_reduce_1024(partPQ, sm);
  double gcur = all_reduce_1024(partRRcur, sm);
  float af = (float)(gcur / pqt);

  int t = threadIdx.x;
  int i = swz_row(blockIdx.x);
  int base = (i << 10) + (t << 2);
  float dg[4]; diag4(i, t, dg);

  double rr = 0.0;
#pragma unroll
  for (int c = 0; c < 3; ++c) {
    Halo hp = load_halo(pNew + c * NV, i, t, base);
    float ns[4]; nsum4(hp, ns);
    float4 rv = *(const float4*)(r + c * NV + base);
    float rA[4] = { rv.x, rv.y, rv.z, rv.w };
    float rn[4], xn[4];
    if (it == 0) {
#pragma unroll
      for (int k = 0; k < 4; ++k) xn[k] = af * hp.m[k];
    } else {
      float4 xv = *(const float4*)(x + c * NV + base);
      xn[0] = xv.x + af * hp.m[0]; xn[1] = xv.y + af * hp.m[1];
      xn[2] = xv.z + af * hp.m[2]; xn[3] = xv.w + af * hp.m[3];
    }
#pragma unroll
    for (int k = 0; k < 4; ++k) {
      float q = dg[k] * hp.m[k] - LAM * ns[k];
      rn[k] = rA[k] - af * q;
      rr += (double)rn[k] * (double)rn[k];
    }
    *(float4*)(r + c * NV + base) = make_float4(rn[0], rn[1], rn[2], rn[3]);
    *(float4*)(x + c * NV + base) = make_float4(xn[0], xn[1], xn[2], xn[3]);
  }
  double tot = blk_reduce_to0(rr, sm);
  if (t == 0) partRRnext[blockIdx.x] = tot;
}

// ---------- x planes -> interleaved verts ----------
__global__ __launch_bounds__(NTHR, 4) void k_xvert(const float* __restrict__ x,
    float* __restrict__ verts) {
  int t = threadIdx.x;
  int i = swz_row(blockIdx.x);
  int vtx = (i << 10) + (t << 2);
  float4 xs = *(const float4*)(x + vtx);
  float4 ys = *(const float4*)(x + NV + vtx);
  float4 zs = *(const float4*)(x + 2 * NV + vtx);
  *(float4*)(verts + 3 * vtx)     = make_float4(xs.x, ys.x, zs.x, xs.y);
  *(float4*)(verts + 3 * vtx + 4) = make_float4(ys.y, zs.y, xs.z, ys.z);
  *(float4*)(verts + 3 * vtx + 8) = make_float4(zs.z, xs.w, ys.w, zs.w);
}

// ---------- faces: read x planes, write centroid + face normals ----------
__device__ __forceinline__ void face_cf(float t0x, float t0y, float t0z,
    float t1x, float t1y, float t1z, float b0x, float b0y, float b0z,
    float* cen, float* fnv) {
  const float third = 1.0f / 3.0f;
  cen[0] = (t0x + t1x + b0x) * third;
  cen[1] = (t0y + t1y + b0y) * third;
  cen[2] = (t0z + t1z + b0z) * third;
  float ax = t1x - t0x, ay = t1y - t0y, az = t1z - t0z;
  float bx = b0x - t0x, by = b0y - t0y, bz = b0z - t0z;
  float cx = ay * bz - az * by;
  float cy = az * bx - ax * bz;
  float cz = ax * by - ay * bx;
  float inv = 1.0f / fmaxf(sqrtf(cx * cx + cy * cy + cz * cz), 1e-12f);
  fnv[0] = cx * inv; fnv[1] = cy * inv; fnv[2] = cz * inv;
}

// No cross-lane ops: the 5th column comes from a guarded scalar load, so
// the t=255 partial tail can't poison neighbors (round-4 bug was a
// divergent-exec __shfl_down).
__global__ __launch_bounds__(NTHR) void k_faces(const float* __restrict__ xp,
    float* __restrict__ cen, float* __restrict__ fn) {
  int ci = blockIdx.x;           // 0..1022
  int t  = threadIdx.x;
  const float* Ps[3] = { xp, xp + NV, xp + 2 * NV };
  int c0 = t << 2;
  int bT = (ci << 10) + c0, bB = bT + GSZ;
  bool full = (t < 255);         // t=255 covers only cols 1020..1022 (3 cells)
  float T[3][5], B[3][5];
#pragma unroll
  for (int p = 0; p < 3; ++p) {
    float4 a = *(const float4*)(Ps[p] + bT);
    T[p][0] = a.x; T[p][1] = a.y; T[p][2] = a.z; T[p][3] = a.w;
    T[p][4] = full ? Ps[p][bT + 4] : 0.f;
    float4 b = *(const float4*)(Ps[p] + bB);
    B[p][0] = b.x; B[p][1] = b.y; B[p][2] = b.z; B[p][3] = b.w;
    B[p][4] = full ? Ps[p][bB + 4] : 0.f;
  }
  float c1[12], f1[12], c2[12], f2[12];
#pragma unroll
  for (int k = 0; k < 4; ++k) {
    // f1 = (v00, v01, v10); f2 = (v01, v11, v10)
    face_cf(T[0][k], T[1][k], T[2][k], T[0][k+1], T[1][k+1], T[2][k+1],
            B[0][k], B[1][k], B[2][k], &c1[3*k], &f1[3*k]);
    face_cf(T[0][k+1], T[1][k+1], T[2][k+1], B[0][k+1], B[1][k+1], B[2][k+1],
            B[0][k], B[1][k], B[2][k], &c2[3*k], &f2[3*k]);
  }
  size_t fb1 = 3 * ((size_t)ci * (GSZ - 1) + c0);
  size_t fb2 = fb1 + 3 * (size_t)FH;
  if (full) {
#pragma unroll
    for (int w = 0; w < 3; ++w) {
      *(f4u*)(cen + fb1 + 4*w) = (f4u){ c1[4*w], c1[4*w+1], c1[4*w+2], c1[4*w+3] };
      *(f4u*)(fn  + fb1 + 4*w) = (f4u){ f1[4*w], f1[4*w+1], f1[4*w+2], f1[4*w+3] };
      *(f4u*)(cen + fb2 + 4*w) = (f4u){ c2[4*w], c2[4*w+1], c2[4*w+2], c2[4*w+3] };
      *(f4u*)(fn  + fb2 + 4*w) = (f4u){ f2[4*w], f2[4*w+1], f2[4*w+2], f2[4*w+3] };
    }
  } else {
    for (int e = 0; e < 9; ++e) {        // 3 cells x 3 comps
      cen[fb1 + e] = c1[e]; fn[fb1 + e] = f1[e];
      cen[fb2 + e] = c2[e]; fn[fb2 + e] = f2[e];
    }
  }
}

// ---------- per-vertex normal: gather <=6 adjacent faces ----------
__global__ __launch_bounds__(256) void k_vn(const float* __restrict__ fn,
    float* __restrict__ vn) {
  int t = blockIdx.x * 256 + threadIdx.x;
  int i = t >> 10, j = t & (GSZ - 1);
  float s0 = 0.f, s1 = 0.f, s2 = 0.f;
  bool iN = (i >= 1), iS = (i <= GSZ-2), jW = (j >= 1), jE = (j <= GSZ-2);
  int rowi = i * (GSZ-1);
#define ADD(fidx) { int f_ = (fidx); s0 += fn[3*f_]; s1 += fn[3*f_+1]; s2 += fn[3*f_+2]; }
  if (iS && jE) ADD(rowi + j);
  if (iS && jW) ADD(rowi + j - 1);
  if (iN && jE) ADD(rowi - (GSZ-1) + j);
  if (iS && jW) ADD(FH + rowi + j - 1);
  if (iN && jW) ADD(FH + rowi - (GSZ-1) + j - 1);
  if (iN && jE) ADD(FH + rowi - (GSZ-1) + j);
#undef ADD
  float nrm = sqrtf(s0*s0 + s1*s1 + s2*s2);
  float inv = 1.0f / fmaxf(nrm, 1e-12f);
  vn[3*t] = s0*inv; vn[3*t+1] = s1*inv; vn[3*t+2] = s2*inv;
}

extern "C" void kernel_launch(void* const* d_in, const int* in_sizes, int n_in,
                              void* d_out, int out_size, void* d_ws, size_t ws_size,
                              hipStream_t stream) {
  const float* u = (const float*)d_in[0];
  float* out = (float*)d_out;

  float* verts = out;
  float* cen   = out + O1;
  float* fn    = out + O2;
  float* vn    = out + O3;

  // CG scratch layout:
  //   x planes -> vn region (out+O3, exactly 3*NV floats); written by k2,
  //     read by k_xvert/k_faces, clobbered only by k_vn (last kernel).
  //   r, p0, p1 planes + doubles -> cen/fn regions (clobbered by k_faces
  //     after CG completes).
  float* xpl   = out + O3;
  float* rpl   = out + O1;
  float* pb[2] = { out + O1 + 3 * (size_t)NV, out + O1 + 6 * (size_t)NV };
  double* D    = (double*)(out + O1 + 9 * (size_t)NV);
  double* partRR = D;           // [2][1024] parity-buffered
  double* partPQ = D + 2048;    // [1024]
  double* slots  = D + 3072;    // [2] gamma parity slots

  k_init<<<dim3(NBLK), dim3(NTHR), 0, stream>>>(u, rpl, partRR /*parity 0*/);

  for (int it = 0; it < CG_ITERS; ++it) {
    const double* prrCur = partRR + (it & 1) * 1024;
    double*       prrNxt = partRR + ((it + 1) & 1) * 1024;
    const float*  pOld   = pb[it & 1];
    float*        pNew   = pb[(it + 1) & 1];
    k1<<<dim3(NBLK), dim3(NTHR), 0, stream>>>(rpl, pOld, pNew,
        prrCur, &slots[it & 1], &slots[(it + 1) & 1], partPQ, it);
    k2<<<dim3(NBLK), dim3(NTHR), 0, stream>>>(pNew, rpl, xpl,
        partPQ, prrCur, prrNxt, it);
  }

  k_xvert<<<dim3(NBLK), dim3(NTHR), 0, stream>>>(xpl, verts);
  k_faces<<<dim3(GSZ - 1), dim3(NTHR), 0, stream>>>(xpl, cen, fn);
  k_vn<<<dim3(NV / 256), dim3(256), 0, stream>>>(fn, vn);
}

// Round 7
// 589.541 us; speedup vs baseline: 16.5423x; 2.3649x over previous
//
#include <hip/hip_runtime.h>

// Problem constants (G=1024 grid, known structure)
#define GSZ   1024
#define NV    (GSZ*GSZ)           // 1048576 vertices
#define N3    (NV*3)              // floats per [NV,3] array
#define FH    ((GSZ-1)*(GSZ-1))   // faces in first half
#define NF    (2*FH)              // total faces
#define O1    N3                  // centroid offset in d_out (floats)
#define O2    (O1 + 3*NF)         // fn offset
#define O3    (O2 + 3*NF)         // vn offset
#define LAM   10.0f
#define CHEB_STEPS 73             // odd: final x lands in buf0 (vn region)

// Chebyshev interval for M = I + 10*L.
// lambda(L) <= 9 EXACTLY: stencil symbol 6-2cos a-2cos b-2cos(a-b) peaks at
// (2pi/3,-2pi/3) -> 9; free-boundary subgraph <= infinite lattice by the
// zero-extension quadratic-form argument. (Round-6 used Anderson-Morley 12
// -> interval [1,121]; too loose, vn missed at 0.031.)
#define CH_LMIN 1.0
#define CH_LMAX 91.0
#define CH_THETA ((CH_LMAX + CH_LMIN) * 0.5)   // 46
#define CH_DELTA ((CH_LMAX - CH_LMIN) * 0.5)   // 45

#define NBLK 1024                 // one block per row
#define NTHR 256                  // thread t covers cols 4t..4t+3

typedef float f4u __attribute__((ext_vector_type(4), aligned(4)));

// XCD-band swizzle: XCD x owns rows [128x, 128x+128)
__device__ __forceinline__ int swz_row(int b) { return ((b & 7) << 7) + (b >> 3); }

// ---------- vectorized stencil halo (exec-uniform: all 256 threads) ----------
struct Halo { float m[4], u[4], d[4]; float mL, mR, uR, dL; };

__device__ __forceinline__ Halo load_halo(const float* __restrict__ pl,
                                          int i, int t, int base) {
  Halo h;
  float4 v = *(const float4*)(pl + base);
  h.m[0] = v.x; h.m[1] = v.y; h.m[2] = v.z; h.m[3] = v.w;
  if (i > 0) {
    v = *(const float4*)(pl + base - GSZ);
    h.u[0] = v.x; h.u[1] = v.y; h.u[2] = v.z; h.u[3] = v.w;
  } else { h.u[0] = h.u[1] = h.u[2] = h.u[3] = 0.f; }
  if (i < GSZ - 1) {
    v = *(const float4*)(pl + base + GSZ);
    h.d[0] = v.x; h.d[1] = v.y; h.d[2] = v.z; h.d[3] = v.w;
  } else { h.d[0] = h.d[1] = h.d[2] = h.d[3] = 0.f; }
  h.mR = __shfl_down(h.m[0], 1, 64);
  h.uR = __shfl_down(h.u[0], 1, 64);
  h.mL = __shfl_up(h.m[3], 1, 64);
  h.dL = __shfl_up(h.d[3], 1, 64);
  int lane = t & 63;
  if (lane == 63) {
    if (t == 255) { h.mR = 0.f; h.uR = 0.f; }
    else { h.mR = pl[base + 4]; h.uR = (i > 0) ? pl[base - GSZ + 4] : 0.f; }
  }
  if (lane == 0) {
    if (t == 0) { h.mL = 0.f; h.dL = 0.f; }
    else { h.mL = pl[base - 1]; h.dL = (i < GSZ - 1) ? pl[base + GSZ - 1] : 0.f; }
  }
  return h;
}

__device__ __forceinline__ void nsum4(const Halo& h, float ns[4]) {
  ns[0] = h.mL   + h.m[1] + h.u[0] + h.d[0] + h.dL   + h.u[1];
  ns[1] = h.m[0] + h.m[2] + h.u[1] + h.d[1] + h.d[0] + h.u[2];
  ns[2] = h.m[1] + h.m[3] + h.u[2] + h.d[2] + h.d[1] + h.u[3];
  ns[3] = h.m[2] + h.mR   + h.u[3] + h.d[3] + h.d[2] + h.uR;
}

__device__ __forceinline__ void diag4(int i, int t, float dg[4]) {
  bool im = (i > 0), ip = (i < GSZ - 1);
#pragma unroll
  for (int k = 0; k < 4; ++k) {
    bool jm = (k > 0) || (t > 0);
    bool jp = (k < 3) || (t < 255);
    int deg = (int)jm + (int)jp + (int)im + (int)ip
            + (int)(ip && jm) + (int)(im && jp);
    dg[k] = 1.0f + LAM * (float)deg;
  }
}

// ---------- init: u (interleaved) -> b planes; x1 = b/theta; x0 = 0 ----------
__global__ __launch_bounds__(NTHR, 4) void k_init(const float* __restrict__ u,
    float* __restrict__ b, float* __restrict__ x1, float* __restrict__ x0) {
  int t = threadIdx.x;
  int i = swz_row(blockIdx.x);
  int vtx = (i << 10) + (t << 2);
  float4 a = *(const float4*)(u + 3 * vtx);
  float4 bb = *(const float4*)(u + 3 * vtx + 4);
  float4 c = *(const float4*)(u + 3 * vtx + 8);
  float4 xs = make_float4(a.x, a.w, bb.z, c.y);
  float4 ys = make_float4(a.y, bb.x, bb.w, c.z);
  float4 zs = make_float4(a.z, bb.y, c.x, c.w);
  *(float4*)(b + vtx)          = xs;
  *(float4*)(b + NV + vtx)     = ys;
  *(float4*)(b + 2 * NV + vtx) = zs;
  const float invth = (float)(1.0 / CH_THETA);
  *(float4*)(x1 + vtx)          = make_float4(xs.x*invth, xs.y*invth, xs.z*invth, xs.w*invth);
  *(float4*)(x1 + NV + vtx)     = make_float4(ys.x*invth, ys.y*invth, ys.z*invth, ys.w*invth);
  *(float4*)(x1 + 2 * NV + vtx) = make_float4(zs.x*invth, zs.y*invth, zs.z*invth, zs.w*invth);
  float4 z4 = make_float4(0.f, 0.f, 0.f, 0.f);
  *(float4*)(x0 + vtx)          = z4;
  *(float4*)(x0 + NV + vtx)     = z4;
  *(float4*)(x0 + 2 * NV + vtx) = z4;
}

// ---------- one Chebyshev step ----------
// x_new = xc + c1*(xc - xo) + c2*(b - A xc); writes into xo's buffer in place
// (xo is only ever read point-wise at this thread's own 4 elements).
__global__ __launch_bounds__(NTHR, 4) void k_cheb(const float* __restrict__ xc,
    float* xo, const float* __restrict__ b, float c1, float c2) {
  int t = threadIdx.x;
  int i = swz_row(blockIdx.x);
  int base = (i << 10) + (t << 2);
  float dg[4]; diag4(i, t, dg);
#pragma unroll
  for (int c = 0; c < 3; ++c) {
    Halo h = load_halo(xc + c * NV, i, t, base);
    float ns[4]; nsum4(h, ns);
    float4 bv = *(const float4*)(b + c * NV + base);
    float4 ov = *(const float4*)(xo + c * NV + base);
    float bA[4] = { bv.x, bv.y, bv.z, bv.w };
    float oA[4] = { ov.x, ov.y, ov.z, ov.w };
    float xn[4];
#pragma unroll
    for (int k = 0; k < 4; ++k) {
      float q = dg[k] * h.m[k] - LAM * ns[k];      // (A xc)_k
      float r = bA[k] - q;                          // residual
      xn[k] = h.m[k] + c1 * (h.m[k] - oA[k]) + c2 * r;
    }
    *(float4*)(xo + c * NV + base) = make_float4(xn[0], xn[1], xn[2], xn[3]);
  }
}

// ---------- x planes -> interleaved verts ----------
__global__ __launch_bounds__(NTHR, 4) void k_xvert(const float* __restrict__ x,
    float* __restrict__ verts) {
  int t = threadIdx.x;
  int i = swz_row(blockIdx.x);
  int vtx = (i << 10) + (t << 2);
  float4 xs = *(const float4*)(x + vtx);
  float4 ys = *(const float4*)(x + NV + vtx);
  float4 zs = *(const float4*)(x + 2 * NV + vtx);
  *(float4*)(verts + 3 * vtx)     = make_float4(xs.x, ys.x, zs.x, xs.y);
  *(float4*)(verts + 3 * vtx + 4) = make_float4(ys.y, zs.y, xs.z, ys.z);
  *(float4*)(verts + 3 * vtx + 8) = make_float4(zs.z, xs.w, ys.w, zs.w);
}

// ---------- faces: read x planes, write centroid + face normals ----------
__device__ __forceinline__ void face_cf(float t0x, float t0y, float t0z,
    float t1x, float t1y, float t1z, float b0x, float b0y, float b0z,
    float* cen, float* fnv) {
  const float third = 1.0f / 3.0f;
  cen[0] = (t0x + t1x + b0x) * third;
  cen[1] = (t0y + t1y + b0y) * third;
  cen[2] = (t0z + t1z + b0z) * third;
  float ax = t1x - t0x, ay = t1y - t0y, az = t1z - t0z;
  float bx = b0x - t0x, by = b0y - t0y, bz = b0z - t0z;
  float cx = ay * bz - az * by;
  float cy = az * bx - ax * bz;
  float cz = ax * by - ay * bx;
  float inv = 1.0f / fmaxf(sqrtf(cx * cx + cy * cy + cz * cz), 1e-12f);
  fnv[0] = cx * inv; fnv[1] = cy * inv; fnv[2] = cz * inv;
}

// No cross-lane ops: 5th column via guarded scalar load (round-4 lesson:
// divergent-exec __shfl_down poisons the last full lane).
__global__ __launch_bounds__(NTHR) void k_faces(const float* __restrict__ xp,
    float* __restrict__ cen, float* __restrict__ fn) {
  int ci = blockIdx.x;           // 0..1022
  int t  = threadIdx.x;
  const float* Ps[3] = { xp, xp + NV, xp + 2 * NV };
  int c0 = t << 2;
  int bT = (ci << 10) + c0, bB = bT + GSZ;
  bool full = (t < 255);         // t=255 covers only cols 1020..1022 (3 cells)
  float T[3][5], B[3][5];
#pragma unroll
  for (int p = 0; p < 3; ++p) {
    float4 a = *(const float4*)(Ps[p] + bT);
    T[p][0] = a.x; T[p][1] = a.y; T[p][2] = a.z; T[p][3] = a.w;
    T[p][4] = full ? Ps[p][bT + 4] : 0.f;
    float4 b = *(const float4*)(Ps[p] + bB);
    B[p][0] = b.x; B[p][1] = b.y; B[p][2] = b.z; B[p][3] = b.w;
    B[p][4] = full ? Ps[p][bB + 4] : 0.f;
  }
  float c1[12], f1[12], c2[12], f2[12];
#pragma unroll
  for (int k = 0; k < 4; ++k) {
    // f1 = (v00, v01, v10); f2 = (v01, v11, v10)
    face_cf(T[0][k], T[1][k], T[2][k], T[0][k+1], T[1][k+1], T[2][k+1],
            B[0][k], B[1][k], B[2][k], &c1[3*k], &f1[3*k]);
    face_cf(T[0][k+1], T[1][k+1], T[2][k+1], B[0][k+1], B[1][k+1], B[2][k+1],
            B[0][k], B[1][k], B[2][k], &c2[3*k], &f2[3*k]);
  }
  size_t fb1 = 3 * ((size_t)ci * (GSZ - 1) + c0);
  size_t fb2 = fb1 + 3 * (size_t)FH;
  if (full) {
#pragma unroll
    for (int w = 0; w < 3; ++w) {
      *(f4u*)(cen + fb1 + 4*w) = (f4u){ c1[4*w], c1[4*w+1], c1[4*w+2], c1[4*w+3] };
      *(f4u*)(fn  + fb1 + 4*w) = (f4u){ f1[4*w], f1[4*w+1], f1[4*w+2], f1[4*w+3] };
      *(f4u*)(cen + fb2 + 4*w) = (f4u){ c2[4*w], c2[4*w+1], c2[4*w+2], c2[4*w+3] };
      *(f4u*)(fn  + fb2 + 4*w) = (f4u){ f2[4*w], f2[4*w+1], f2[4*w+2], f2[4*w+3] };
    }
  } else {
    for (int e = 0; e < 9; ++e) {        // 3 cells x 3 comps
      cen[fb1 + e] = c1[e]; fn[fb1 + e] = f1[e];
      cen[fb2 + e] = c2[e]; fn[fb2 + e] = f2[e];
    }
  }
}

// ---------- per-vertex normal: gather <=6 adjacent faces ----------
__global__ __launch_bounds__(256) void k_vn(const float* __restrict__ fn,
    float* __restrict__ vn) {
  int t = blockIdx.x * 256 + threadIdx.x;
  int i = t >> 10, j = t & (GSZ - 1);
  float s0 = 0.f, s1 = 0.f, s2 = 0.f;
  bool iN = (i >= 1), iS = (i <= GSZ-2), jW = (j >= 1), jE = (j <= GSZ-2);
  int rowi = i * (GSZ-1);
#define ADD(fidx) { int f_ = (fidx); s0 += fn[3*f_]; s1 += fn[3*f_+1]; s2 += fn[3*f_+2]; }
  if (iS && jE) ADD(rowi + j);
  if (iS && jW) ADD(rowi + j - 1);
  if (iN && jE) ADD(rowi - (GSZ-1) + j);
  if (iS && jW) ADD(FH + rowi + j - 1);
  if (iN && jW) ADD(FH + rowi - (GSZ-1) + j - 1);
  if (iN && jE) ADD(FH + rowi - (GSZ-1) + j);
#undef ADD
  float nrm = sqrtf(s0*s0 + s1*s1 + s2*s2);
  float inv = 1.0f / fmaxf(nrm, 1e-12f);
  vn[3*t] = s0*inv; vn[3*t+1] = s1*inv; vn[3*t+2] = s2*inv;
}

extern "C" void kernel_launch(void* const* d_in, const int* in_sizes, int n_in,
                              void* d_out, int out_size, void* d_ws, size_t ws_size,
                              hipStream_t stream) {
  const float* u = (const float*)d_in[0];
  float* out = (float*)d_out;

  float* verts = out;
  float* cen   = out + O1;
  float* fn    = out + O2;
  float* vn    = out + O3;

  // Scratch: x buffers ping-pong; buf0 in the vn region (out+O3, exactly
  // 3*NV floats), buf1 + b planes in the cen/fn region (clobbered only by
  // k_faces after the solve). CHEB_STEPS is odd so the final x lands in
  // buf0 (vn region) -- k_faces must not read from the region it writes.
  float* buf0 = out + O3;
  float* buf1 = out + O1;
  float* bpl  = out + O1 + 3 * (size_t)NV;

  // init: b planes; x1 = b/theta into buf1; x0 = 0 into buf0
  k_init<<<dim3(NBLK), dim3(NTHR), 0, stream>>>(u, bpl, buf1, buf0);

  // Chebyshev semi-iteration, coefficients precomputed on host (double).
  double s1 = CH_THETA / CH_DELTA;
  double rho_p = 1.0 / s1;
  float* bufs[2] = { buf0, buf1 };
  int cur = 1;                      // x_k in bufs[cur], x_{k-1} in bufs[1-cur]
  for (int k = 1; k <= CHEB_STEPS; ++k) {
    double rho = 1.0 / (2.0 * s1 - rho_p);
    float c1 = (float)(rho * rho_p);
    float c2 = (float)(2.0 * rho / CH_DELTA);
    k_cheb<<<dim3(NBLK), dim3(NTHR), 0, stream>>>(bufs[cur], bufs[1 - cur],
                                                  bpl, c1, c2);
    rho_p = rho;
    cur ^= 1;                       // new x now in bufs[cur]
  }
  float* xf = bufs[cur];            // final x planes (= buf0, odd steps)

  k_xvert<<<dim3(NBLK), dim3(NTHR), 0, stream>>>(xf, verts);
  k_faces<<<dim3(GSZ - 1), dim3(NTHR), 0, stream>>>(xf, cen, fn);
  k_vn<<<dim3(NV / 256), dim3(256), 0, stream>>>(fn, vn);
}